// Round 13
// baseline (230.057 us; speedup 1.0000x reference)
//
#include <hip/hip_runtime.h>

#define NQ 10000
#define BS 2
#define NV 19560
#define NH 8
#define HD 32
#define EMB 256

typedef __attribute__((ext_vector_type(8))) short bf16x8;
typedef __attribute__((ext_vector_type(4))) float f32x4;
typedef __attribute__((ext_vector_type(4))) short s16x4;

__device__ __forceinline__ unsigned short f2bf(float x) {
    unsigned u = __float_as_uint(x);
    u += 0x7FFFu + ((u >> 16) & 1u);       // RNE
    return (unsigned short)(u >> 16);
}

// ---------------------------------------------------------------------------
// Transpose weights into Bt[n][k] bf16 (rows 0-255 W_val, 256-511 W_off,
// 512-639 W_attn) + concat biases. [r10 proven, verbatim]
// ---------------------------------------------------------------------------
__global__ __launch_bounds__(256) void convert_W(
    const float* __restrict__ Wv, const float* __restrict__ Wo,
    const float* __restrict__ Wa, const float* __restrict__ bv,
    const float* __restrict__ bo, const float* __restrict__ ba,
    ushort* __restrict__ Bt, float* __restrict__ bias) {
    int n = blockIdx.x;      // 0..639
    int k = threadIdx.x;     // 0..255
    float x;
    if (n < 256)       x = Wv[k * 256 + n];
    else if (n < 512)  x = Wo[k * 256 + (n - 256)];
    else               x = Wa[k * 128 + (n - 512)];
    Bt[n * 256 + k] = f2bf(x);
    if (k == 0)
        bias[n] = (n < 256) ? bv[n] : (n < 512) ? bo[n - 256] : ba[n - 512];
}

// ---------------------------------------------------------------------------
// Fused GEMM, one dispatch for both projections. r10 tile (64m x 128n, wave
// tile 32m x 64n) upgraded to BK=64 (8 barriers/block instead of 16) with a
// REGISTER double-buffer: k+1's global loads issue before the MFMA section,
// so the vmcnt(0) drain at the barrier finds them complete (latency covered
// by compute, not exposed). Staging/fragment/epilogue index math = r10 forms.
// Coverage: A 256thr x 16 fp32 = 64x64 ; B 256thr x 32 sh = 128x64.
// ---------------------------------------------------------------------------
__global__ __launch_bounds__(256) void gemm_fused(
    const float* __restrict__ value, const float* __restrict__ query,
    const float* __restrict__ qpos, const ushort* __restrict__ Bt,
    const float* __restrict__ bias,
    ushort* __restrict__ Cv, float* __restrict__ C0, float* __restrict__ C1)
{
    __shared__ short As[64][72], Bhs[128][72];  // pad 64->72 (144B rows)

    const int tid = threadIdx.x;
    const int bid = blockIdx.x;
    bool isval; int mblk, npan;
    if (bid < 1224) { isval = true;  mblk = bid >> 1; npan = bid & 1; }
    else { int q = bid - 1224; isval = false; mblk = q / 3; npan = q % 3; }

    const int M  = isval ? (BS * NV) : (BS * NQ);
    const int m0 = mblk * 64;
    const int n0 = npan * 128;
    const int nbase = (isval ? 0 : 256) + n0;

    const float* A = isval ? value : query;

    // A staging: thread t -> row t>>2 (0..63), k-chunk (t&3)*16
    const int arow = tid >> 2;
    const int acol = (tid & 3) * 16;
    const bool aval = (m0 + arow) < M;
    const float* Ap  = A    + (size_t)(m0 + arow) * 256 + acol;
    const float* A2p = qpos + (size_t)(m0 + arow) * 256 + acol;
    // B staging: thread t -> row t>>1 (0..127), k-half (t&1)*32
    const int brow = tid >> 1;
    const int bcol = (tid & 1) * 32;
    const ushort* Bp = Bt + (size_t)(nbase + brow) * 256 + bcol;

    const int lane = tid & 63, wave = tid >> 6;
    const int wrow = (wave >> 1) * 32, wcol = (wave & 1) * 64;
    const int lr = lane & 15, quad = lane >> 4;

    f32x4 aR[4]; bf16x8 bR[4];

    // ---- prologue: load k-block 0 into regs, store to LDS ----
    #pragma unroll
    for (int g = 0; g < 4; g++) {
        f32x4 v = {};
        if (aval) {
            v = *(const f32x4*)(Ap + g * 4);
            if (!isval) v += *(const f32x4*)(A2p + g * 4);
        }
        aR[g] = v;
    }
    #pragma unroll
    for (int c = 0; c < 4; c++) bR[c] = *(const bf16x8*)(Bp + c * 8);
    #pragma unroll
    for (int g = 0; g < 4; g++) {
        s16x4 hh;
        #pragma unroll
        for (int e = 0; e < 4; e++) hh[e] = (short)f2bf(aR[g][e]);
        *(s16x4*)&As[arow][acol + g * 4] = hh;
    }
    #pragma unroll
    for (int c = 0; c < 4; c++) *(bf16x8*)&Bhs[brow][bcol + c * 8] = bR[c];
    __syncthreads();

    f32x4 acc[2][4] = {};

    #pragma unroll
    for (int k0 = 0; k0 < 256; k0 += 64) {
        // ---- prefetch k0+64 into registers (overlaps MFMA below) ----
        if (k0 < 192) {
            #pragma unroll
            for (int g = 0; g < 4; g++) {
                f32x4 v = {};
                if (aval) {
                    v = *(const f32x4*)(Ap + k0 + 64 + g * 4);
                    if (!isval) v += *(const f32x4*)(A2p + k0 + 64 + g * 4);
                }
                aR[g] = v;
            }
            #pragma unroll
            for (int c = 0; c < 4; c++)
                bR[c] = *(const bf16x8*)(Bp + k0 + 64 + c * 8);
        }
        // ---- compute on LDS k-block (two BK=32 sub-steps) ----
        #pragma unroll
        for (int sub = 0; sub < 2; sub++) {
            const int lk = sub * 32 + quad * 8;
            bf16x8 af[2], bhf[4];
            #pragma unroll
            for (int i = 0; i < 2; i++)
                af[i] = *(const bf16x8*)&As[wrow + i * 16 + lr][lk];
            #pragma unroll
            for (int j = 0; j < 4; j++)
                bhf[j] = *(const bf16x8*)&Bhs[wcol + j * 16 + lr][lk];
            #pragma unroll
            for (int i = 0; i < 2; i++)
                #pragma unroll
                for (int j = 0; j < 4; j++)
                    acc[i][j] = __builtin_amdgcn_mfma_f32_16x16x32_bf16(af[i], bhf[j], acc[i][j], 0, 0, 0);
        }
        __syncthreads();
        // ---- write prefetched regs to LDS ----
        if (k0 < 192) {
            #pragma unroll
            for (int g = 0; g < 4; g++) {
                s16x4 hh;
                #pragma unroll
                for (int e = 0; e < 4; e++) hh[e] = (short)f2bf(aR[g][e]);
                *(s16x4*)&As[arow][acol + g * 4] = hh;
            }
            #pragma unroll
            for (int c = 0; c < 4; c++)
                *(bf16x8*)&Bhs[brow][bcol + c * 8] = bR[c];
        }
        __syncthreads();
    }

    // ---- epilogue (r10 proven mapping, verbatim) ----
    #pragma unroll
    for (int j = 0; j < 4; j++) {
        int cc = wcol + j * 16 + lr;
        int col = n0 + cc;
        float bb = bias[nbase + cc];
        #pragma unroll
        for (int i = 0; i < 2; i++) {
            int gmb = m0 + wrow + i * 16 + quad * 4;
            #pragma unroll
            for (int r = 0; r < 4; r++) {
                int gm = gmb + r;
                if (gm < M) {
                    float val = acc[i][j][r] + bb;
                    if (isval) {
                        int h = col >> 5, d = col & 31;
                        int b = (gm >= NV) ? 1 : 0;
                        int pix = gm - b * NV;
                        Cv[((size_t)(b * 8 + h) * NV + pix) * 32 + d] = f2bf(val);
                    } else {
                        if (col < 256) C0[(size_t)gm * 256 + col] = val;
                        else           C1[(size_t)gm * 128 + (col - 256)] = val;
                    }
                }
            }
        }
    }
}

// ---------------------------------------------------------------------------
// Sampler v7: r12's proven inner structure, re-blocked to 64 threads / 2
// queries per block (10000 blocks, LDS 8.4 KB) -> ~4x residency headroom for
// latency hiding. Phase 1 (4 reps): one thread per (q,h,l,p): softmax
// (shuffle w16) + pixel coords + clamped corner offsets + validity-
// premultiplied weights -> LDS (stride-66 rows). Phase 2: 4 lanes per (q,h),
// lane = 8 channels (dwordx4), 2-point batches (8 loads in flight), 8 accs.
// ---------------------------------------------------------------------------
__global__ __launch_bounds__(64) void sample7(
    const ushort* __restrict__ v, const float* __restrict__ off,
    const float* __restrict__ attn, const float* __restrict__ refp,
    float* __restrict__ out)
{
    __shared__ int   s_off[16][66];
    __shared__ float s_w[16][66];

    const int bq0 = blockIdx.x * 2;
    const int t = threadIdx.x;

    #pragma unroll
    for (int rep = 0; rep < 4; rep++) {
        const int id = rep * 64 + t;       // 0..255
        const int g = id >> 4;             // group = qi*8 + h  (0..15)
        const int qi = g >> 3, h = g & 7;
        const int bq = bq0 + qi;
        const int b = (bq >= NQ) ? 1 : 0;
        const int i = id & 15;             // point = l*4 + p
        const int l = i >> 2, p = i & 3;

        float logit = attn[(size_t)bq * 128 + h * 16 + i];
        float mx = logit;
        #pragma unroll
        for (int m = 1; m < 16; m <<= 1) mx = fmaxf(mx, __shfl_xor(mx, m, 16));
        float e = __expf(logit - mx);
        float s = e;
        #pragma unroll
        for (int m = 1; m < 16; m <<= 1) s += __shfl_xor(s, m, 16);
        float w = e / s;

        const float Wf[4] = {160.f, 80.f, 40.f, 20.f};
        const float Hf[4] = {92.f, 46.f, 23.f, 12.f};
        const int   Wi[4] = {160, 80, 40, 20};
        const int   Hi[4] = {92, 46, 23, 12};
        const int   st[4] = {0, 14720, 18400, 19320};

        float ox = off[(size_t)bq * 256 + h * 32 + l * 8 + p * 2];
        float oy = off[(size_t)bq * 256 + h * 32 + l * 8 + p * 2 + 1];
        float rx = refp[(size_t)bq * 8 + p * 2];
        float ry = refp[(size_t)bq * 8 + p * 2 + 1];
        float x = rx * Wf[l] + ox - 0.5f;
        float y = ry * Hf[l] + oy - 0.5f;
        float x0f = floorf(x), y0f = floorf(y);
        float wx1 = x - x0f, wy1 = y - y0f;
        float wx0 = 1.f - wx1, wy0 = 1.f - wy1;
        int x0 = (int)x0f, y0 = (int)y0f;
        const int W = Wi[l], H = Hi[l];
        float mx0 = ((unsigned)x0       < (unsigned)W) ? 1.f : 0.f;
        float mx1 = ((unsigned)(x0 + 1) < (unsigned)W) ? 1.f : 0.f;
        float my0 = ((unsigned)y0       < (unsigned)H) ? 1.f : 0.f;
        float my1 = ((unsigned)(y0 + 1) < (unsigned)H) ? 1.f : 0.f;
        int xc0 = min(max(x0, 0), W - 1);
        int xc1 = min(max(x0 + 1, 0), W - 1);
        int yc0 = min(max(y0, 0), H - 1);
        int yc1 = min(max(y0 + 1, 0), H - 1);
        int base = ((b * 8 + h) * NV + st[l]) * 32;
        s_off[g][i * 4 + 0] = base + (yc0 * W + xc0) * 32;
        s_off[g][i * 4 + 1] = base + (yc0 * W + xc1) * 32;
        s_off[g][i * 4 + 2] = base + (yc1 * W + xc0) * 32;
        s_off[g][i * 4 + 3] = base + (yc1 * W + xc1) * 32;
        s_w[g][i * 4 + 0] = w * wy0 * wx0 * my0 * mx0;
        s_w[g][i * 4 + 1] = w * wy0 * wx1 * my0 * mx1;
        s_w[g][i * 4 + 2] = w * wy1 * wx0 * my1 * mx0;
        s_w[g][i * 4 + 3] = w * wy1 * wx1 * my1 * mx1;
    }
    __syncthreads();

    const int g  = t >> 2;          // 0..15: (qi, h)
    const int c4 = t & 3;           // 8-channel slice
    const int qi = g >> 3, h = g & 7;
    const int bq = bq0 + qi;
    const int d8 = c4 * 8;

    float a0=0.f,a1=0.f,a2=0.f,a3=0.f,a4=0.f,a5=0.f,a6=0.f,a7=0.f;
    #pragma unroll
    for (int i = 0; i < 16; i += 2) {       // 2 points = 8 corner loads/batch
        int o[8]; float wgt[8];
        #pragma unroll
        for (int pp = 0; pp < 2; pp++)
            #pragma unroll
            for (int c = 0; c < 4; c++) {
                o[pp * 4 + c]   = s_off[g][(i + pp) * 4 + c];
                wgt[pp * 4 + c] = s_w[g][(i + pp) * 4 + c];
            }
        uint4 u[8];
        #pragma unroll
        for (int j = 0; j < 8; j++)
            u[j] = *(const uint4*)(v + o[j] + d8);
        #pragma unroll
        for (int j = 0; j < 8; j++) {
            float w = wgt[j];
            a0 += w * __uint_as_float(u[j].x << 16);
            a1 += w * __uint_as_float(u[j].x & 0xffff0000u);
            a2 += w * __uint_as_float(u[j].y << 16);
            a3 += w * __uint_as_float(u[j].y & 0xffff0000u);
            a4 += w * __uint_as_float(u[j].z << 16);
            a5 += w * __uint_as_float(u[j].z & 0xffff0000u);
            a6 += w * __uint_as_float(u[j].w << 16);
            a7 += w * __uint_as_float(u[j].w & 0xffff0000u);
        }
    }
    float* op = out + (size_t)bq * 256 + h * 32 + d8;
    f32x4 r0 = {a0, a1, a2, a3};
    f32x4 r1 = {a4, a5, a6, a7};
    *(f32x4*)op       = r0;
    *(f32x4*)(op + 4) = r1;
}

extern "C" void kernel_launch(void* const* d_in, const int* in_sizes, int n_in,
                              void* d_out, int out_size, void* d_ws, size_t ws_size,
                              hipStream_t stream) {
    const float* query     = (const float*)d_in[0];
    const float* value     = (const float*)d_in[1];
    const float* query_pos = (const float*)d_in[2];
    const float* refp      = (const float*)d_in[3];
    const float* W_val     = (const float*)d_in[4];
    const float* b_val     = (const float*)d_in[5];
    const float* W_off     = (const float*)d_in[6];
    const float* b_off     = (const float*)d_in[7];
    const float* W_attn    = (const float*)d_in[8];
    const float* b_attn    = (const float*)d_in[9];
    float* out = (float*)d_out;

    char* w = (char*)d_ws;
    float*  off    = (float*)w;   w += 20480000;   // 20000 x 256 fp32
    float*  attn   = (float*)w;   w += 10240000;   // 20000 x 128 fp32
    ushort* vp_bf  = (ushort*)w;  w += 20029440;   // planar (b,h,NV,32) bf16
    ushort* Bt     = (ushort*)w;  w += 327680;     // 640 x 256 bf16
    float*  bias_c = (float*)w;   w += 2560;

    convert_W<<<640, 256, 0, stream>>>(W_val, W_off, W_attn, b_val, b_off, b_attn,
                                       Bt, bias_c);

    // one dispatch: value-proj (1224 blocks) + query-proj (939 blocks)
    gemm_fused<<<1224 + 939, 256, 0, stream>>>(value, query, query_pos, Bt, bias_c,
                                               vp_bf, off, attn);

    // fused softmax + loc + bilinear sample (2 queries per 64-thread block)
    sample7<<<BS * NQ / 2, 64, 0, stream>>>(vp_bf, off, attn, refp, out);
}